// Round 5
// baseline (759.187 us; speedup 1.0000x reference)
//
#include <hip/hip_runtime.h>
#include <cstdint>

#define DEV __device__ __forceinline__

static constexpr float INV_SQRT_W = 0.04419417382415922f; // 1/sqrt(512)
static constexpr float SQRT2_F    = 1.41421356237309515f;

typedef _Float16 half8 __attribute__((ext_vector_type(8)));
typedef float    f32x4 __attribute__((ext_vector_type(4)));

#define GLL16(g, l) __builtin_amdgcn_global_load_lds( \
    (const __attribute__((address_space(1))) void*)(g), \
    (__attribute__((address_space(3))) void*)(l), 16, 0, 0)

DEV int imax(int a, int b) { return a > b ? a : b; }
DEV int imin(int a, int b) { return a < b ? a : b; }

// styles[n][c] = w[n]·aw[c] / sqrt(512) + ab[c]
__global__ __launch_bounds__(256) void k_styles(const float* __restrict__ w,
    const float* __restrict__ aw, const float* __restrict__ ab,
    float* __restrict__ styles) {
  int t = blockIdx.x * 256 + threadIdx.x;        // 4096
  int n = t >> 9, c = t & 511;
  const float* wr = w + n * 512;
  const float* ar = aw + c * 512;
  float s = 0.f;
  for (int k = 0; k < 512; ++k) s = fmaf(wr[k], ar[k], s);
  styles[t] = s * INV_SQRT_W + ab[c];
}

// wsq[o][i] = sum_k w[o,i,k]^2 ; wscale[o] = rsqrt(mean over 4608)
__global__ __launch_bounds__(256) void k_wstats(const float* __restrict__ cw,
    float* __restrict__ wsq, float* __restrict__ wscale) {
  int o = blockIdx.x;
  __shared__ float red[256];
  float tot = 0.f;
  for (int i = threadIdx.x; i < 512; i += 256) {
    const float* p = cw + (o * 512 + i) * 9;
    float s = 0.f;
#pragma unroll
    for (int k = 0; k < 9; ++k) s = fmaf(p[k], p[k], s);
    wsq[o * 512 + i] = s;
    tot += s;
  }
  red[threadIdx.x] = tot;
  __syncthreads();
  for (int st = 128; st > 0; st >>= 1) {
    if (threadIdx.x < st) red[threadIdx.x] += red[threadIdx.x + st];
    __syncthreads();
  }
  if (threadIdx.x == 0) wscale[o] = rsqrtf(red[0] / 4608.f);
}

// sg = rsqrt(mean(styles^2)) over all 4096
__global__ __launch_bounds__(256) void k_sg(const float* __restrict__ styles,
                                            float* __restrict__ sg) {
  __shared__ float red[256];
  float s = 0.f;
  for (int t = threadIdx.x; t < 4096; t += 256) { float v = styles[t]; s = fmaf(v, v, s); }
  red[threadIdx.x] = s;
  __syncthreads();
  for (int st = 128; st > 0; st >>= 1) {
    if (threadIdx.x < st) red[threadIdx.x] += red[threadIdx.x + st];
    __syncthreads();
  }
  if (threadIdx.x == 0) sg[0] = rsqrtf(red[0] / 4096.f);
}

// coef[n][o] = ig * rsqrt(a^2*Q + 1e-8), a = wscale[o]*sg
__global__ __launch_bounds__(256) void k_coef(const float* __restrict__ styles,
    const float* __restrict__ wsq, const float* __restrict__ wscale,
    const float* __restrict__ sg, const float* __restrict__ ema,
    float* __restrict__ coef) {
  int n = blockIdx.x >> 1;
  int o = ((blockIdx.x & 1) << 8) + threadIdx.x;
  __shared__ float s2[512];
  for (int i = threadIdx.x; i < 512; i += 256) { float v = styles[n * 512 + i]; s2[i] = v * v; }
  __syncthreads();
  const float* wq = wsq + o * 512;
  float Q = 0.f;
  for (int i = 0; i < 512; ++i) Q = fmaf(s2[i], wq[i], Q);
  float a = wscale[o] * sg[0];
  float ig = rsqrtf(ema[0]);
  coef[n * 512 + o] = ig * rsqrtf(a * a * Q + 1e-8f);
}

// xT[n][ic][r][c][slot s][j] = f16( x[n, ic*32 + (s^sig(r,c))*8+j, r, c] * styles * sg )
__global__ __launch_bounds__(256) void k_xprep(const float* __restrict__ x,
    const float* __restrict__ styles, const float* __restrict__ sg,
    _Float16* __restrict__ xT) {
  const int b = blockIdx.x;                 // 8*16*64 = 8192
  const int r = b & 63, ic = (b >> 6) & 15, n = b >> 10;
  const int tid = threadIdx.x;
  const int c = tid >> 2, s = tid & 3;
  const float sgv = sg[0];
  const int sig = ((r * 68 + c + 2) >> 1) & 3;
  const int i0 = ic * 32 + (s ^ sig) * 8;
  half8 v;
#pragma unroll
  for (int j = 0; j < 8; ++j) {
    int i = i0 + j;
    float xv = x[(((size_t)n * 512 + i) * 64 + r) * 64 + c];
    v[j] = (_Float16)(xv * styles[n * 512 + i] * sgv);
  }
  *(half8*)(xT + ((((size_t)(n * 16 + ic) * 64 + r) * 64 + c) * 32) + s * 8) = v;
}

// w2[k9][ic][o][iw] = f16( cw[o, ic*32+iw, k9] * wscale[o] )
__global__ __launch_bounds__(256) void k_wprep(const float* __restrict__ cw,
    const float* __restrict__ wscale, _Float16* __restrict__ w2) {
  int t = blockIdx.x * 256 + threadIdx.x;    // 294912 slots of 8 halfs
  int s = t & 3;
  int o = (t >> 2) & 511;
  int ic = (t >> 11) & 15;
  int k9 = t >> 15;                          // 0..8
  float wsc = wscale[o];
  half8 v;
#pragma unroll
  for (int j = 0; j < 8; ++j) {
    int i = ic * 32 + s * 8 + j;
    v[j] = (_Float16)(cw[((size_t)o * 512 + i) * 9 + k9] * wsc);
  }
  *(half8*)(w2 + (size_t)t * 8) = v;
}

// Implicit-GEMM conv via MFMA f16.
// Block: 128 o x 198 p (exactly 3 output rows). 704 blocks, all resident at
// 3 blocks/CU (LDS 43.5KB). XCD swizzle: each XCD owns one full image n.
__global__ __launch_bounds__(256, 3) void k_conv(
    const _Float16* __restrict__ xT, const _Float16* __restrict__ w2,
    const float* __restrict__ coef, float* __restrict__ convout) {
  // bijective XCD swizzle: 704 = 8 * 88; XCD k handles lin in [k*88,(k+1)*88) = image n=k
  const int b = blockIdx.x;
  const int lin = (b & 7) * 88 + (b >> 3);
  const int n = lin / 88;
  const int rem = lin - n * 88;
  const int pt = rem >> 2;                 // 0..21
  const int ot = rem & 3;                  // 0..3
  const int p0 = pt * 198;
  const int R0 = pt * 3;
  const int oBase = ot * 128;

  const int tid = threadIdx.x;
  const int wave = tid >> 6;
  const int lane = tid & 63;
  const int wo = wave >> 1, wp = wave & 1;
  const int isub = lane >> 4;
  const int l15 = lane & 15;

  __shared__ _Float16 patch[2][10880];   // [5][68][32] halfs each, 21760 B per buf

  // per-nt fragment coords: 7 frags cover 99 p per (wp) half-tile
  int lbase[7], sigb[7]; bool valid[7];
#pragma unroll
  for (int nt = 0; nt < 7; ++nt) {
    int local = wp * 99 + nt * 16 + l15;
    valid[nt] = (local < 198);
    int pl = valid[nt] ? local : 197;
    int p = p0 + pl;
    int r = p / 66;
    int c = p - r * 66;
    lbase[nt] = ((r - R0) * 68 + c) * 32;  // LDS offset (dr,dc added later)
    sigb[nt] = (r - 2) * 68 + c;           // swizzle argument base
  }

  f32x4 acc[4][7];
#pragma unroll
  for (int mt = 0; mt < 4; ++mt)
#pragma unroll
    for (int nt = 0; nt < 7; ++nt) acc[mt][nt] = (f32x4){0.f, 0.f, 0.f, 0.f};

  const int oA = oBase + wo * 64 + l15;
  const _Float16* wp0 = w2 + (size_t)oA * 32 + isub * 8;  // + ((k9*16+ic)*512 + mt*16)*32

  auto stage_patch = [&](int ic, int buf) {
    const _Float16* src = xT + ((size_t)(n * 16 + ic) * 4096) * 32;
    _Float16* dst = &patch[buf][0];
#pragma unroll
    for (int rl = 0; rl < 5; ++rl) {
      int rin = R0 - 2 + rl;
      if (rin >= 0 && rin < 64)
        GLL16(src + (size_t)rin * 2048 + tid * 8, dst + (rl * 68 + 2) * 32 + tid * 8);
    }
    if (tid < 80) {                       // side pad cols: 5 rows x {0,1,66,67} x 4 slots
      int pix = tid >> 2, s = tid & 3;
      int rl = pix >> 2, ci = pix & 3;
      int cl = (ci < 2) ? ci : (ci + 64);
      half8 z = {};
      *(half8*)(dst + (rl * 68 + cl) * 32 + s * 8) = z;
    }
#pragma unroll
    for (int rl = 0; rl < 5; ++rl) {
      int rin = R0 - 2 + rl;
      if (rin < 0 || rin >= 64) {
        for (int u = tid; u < 272; u += 256) {   // 68 pixels x 4 slots
          half8 z = {};
          *(half8*)(dst + rl * 68 * 32 + u * 8) = z;
        }
      }
    }
  };

  stage_patch(0, 0);
  __syncthreads();

  for (int ic = 0; ic < 16; ++ic) {
    const int buf = ic & 1;
    if (ic < 15) stage_patch(ic + 1, buf ^ 1);
    const _Float16* pb = &patch[buf][0];

#pragma unroll
    for (int k9 = 0; k9 < 9; ++k9) {
      const int dr = k9 / 3, dc = k9 % 3;
      const int d68 = dr * 68 + dc;
      half8 aF[4];
#pragma unroll
      for (int mt = 0; mt < 4; ++mt)
        aF[mt] = *(const half8*)(wp0 + ((size_t)(k9 * 16 + ic) * 512 + mt * 16) * 32);
#pragma unroll
      for (int nt = 0; nt < 7; ++nt) {
        int sig = ((sigb[nt] + d68) >> 1) & 3;
        int ah = lbase[nt] + d68 * 32 + ((isub ^ sig) << 3);
        half8 bF = *(const half8*)(pb + ah);
#pragma unroll
        for (int mt = 0; mt < 4; ++mt)
          acc[mt][nt] = __builtin_amdgcn_mfma_f32_16x16x32_f16(aF[mt], bF, acc[mt][nt], 0, 0, 0);
      }
    }
    __syncthreads();
  }

  // epilogue: C layout col=lane&15 (p), row=isub*4+j (o); scale by coef
#pragma unroll
  for (int mt = 0; mt < 4; ++mt) {
    const int o = oBase + wo * 64 + mt * 16 + isub * 4;
#pragma unroll
    for (int j = 0; j < 4; ++j) {
      const float cf = coef[n * 512 + o + j];
      float* outp = convout + ((size_t)(n * 512) + o + j) * 4356;
#pragma unroll
      for (int nt = 0; nt < 7; ++nt) {
        if (valid[nt]) {
          int p = p0 + wp * 99 + nt * 16 + l15;
          outp[p] = acc[mt][nt][j] * cf;
        }
      }
    }
  }
}

// Fused bias + up-FIR(x2, polyphase) + lrelu + clamp + down-FIR(/2).
// NO cross-lane LDS sharing (R3 lesson). Verified in R4 — unchanged.
__global__ __launch_bounds__(256) void k_flrelu(const float* __restrict__ convout,
    const float* __restrict__ cbias, const float* __restrict__ fu,
    const float* __restrict__ fd, float* __restrict__ out) {
  const int img = blockIdx.x >> 2;       // n*512+c
  const int tile = blockIdx.x & 3;
  const int p0 = tile * 16;              // output rows [p0, p0+16)
  const int c = img & 511;
  const int tid = threadIdx.x;
  const int wv = tid >> 6, ln = tid & 63;

  __shared__ float As[26 * 68];          // conv rows p0-4 .. p0+21 (+bias), 0 outside
  __shared__ float Bs[42 * 76];          // v-up rows, col offset +4, zero aprons
  __shared__ float Vs[42 * 64];          // after horizontal up+lrelu+down

  float fupr[12], fdr[12];
#pragma unroll
  for (int j = 0; j < 12; ++j) { fupr[j] = fu[j]; fdr[j] = fd[11 - j]; }

  // stage 1: A rows [p0-4, p0+21] + bias; zero outside image
  {
    const float* src = convout + (size_t)img * 4356;
    const float bias = cbias[c];
    for (int t = tid; t < 26 * 68; t += 256) {
      int r = t / 68, cc2 = t - r * 68;
      int gr = p0 - 4 + r;
      float v = 0.f;
      if (cc2 < 66 && gr >= 0 && gr < 66) v = src[gr * 66 + cc2] + bias;
      As[t] = v;
    }
  }
  __syncthreads();

  // stage 2: vertical up-FIR, polyphase 6 taps
  for (int t = tid; t < 42 * 33; t += 256) {
    int k = t / 33, m2 = t - k * 33;
    int e = k & 1, kk = (k - e) >> 1;
    const float* Ab = &As[kk * 68 + 2 * m2];
    float sx = 0.f, sy = 0.f;
#pragma unroll
    for (int j = 0; j < 6; ++j) {
      float2 a = *(const float2*)(Ab + (5 - j) * 68);
      float f = e ? fupr[2 * j + 1] : fupr[2 * j];
      sx = fmaf(f, a.x, sx);
      sy = fmaf(f, a.y, sy);
    }
    float2 s2v = make_float2(sx, sy);
    *(float2*)&Bs[k * 76 + 4 + 2 * m2] = s2v;
  }
  for (int t = tid; t < 42 * 10; t += 256) {
    int k = t / 10, ci = t - k * 10;
    int col = (ci < 4) ? ci : (66 + ci);
    Bs[k * 76 + col] = 0.f;
  }
  __syncthreads();

  // stage 3: per-lane recompute of upsampled row + lrelu + horizontal down
  for (int k = wv; k < 42; k += 4) {
    const float* Br = &Bs[k * 76 + ln];
    float b[11];
#pragma unroll
    for (int t = 0; t < 11; ++t) b[t] = Br[t];
    float v = 0.f;
#pragma unroll
    for (int d = 0; d < 6; ++d) {
      float ue = 0.f, uo = 0.f;
#pragma unroll
      for (int j = 0; j < 6; ++j) {
        float bb = b[d + 5 - j];
        ue = fmaf(fupr[2 * j], bb, ue);
        uo = fmaf(fupr[2 * j + 1], bb, uo);
      }
      ue *= (ue >= 0.f) ? 5.65685424949238f : 1.13137084989848f;
      uo *= (uo >= 0.f) ? 5.65685424949238f : 1.13137084989848f;
      ue = fminf(256.f, fmaxf(-256.f, ue));
      uo = fminf(256.f, fmaxf(-256.f, uo));
      v = fmaf(fdr[2 * d], ue, v);
      v = fmaf(fdr[2 * d + 1], uo, v);
    }
    Vs[k * 64 + ln] = v;
  }
  __syncthreads();

  // stage 4: vertical down-FIR -> out rows [p0, p0+16)
  for (int t = tid; t < 1024; t += 256) {
    int pr = t >> 6, q = t & 63;
    const float* Vb = &Vs[2 * pr * 64 + q];
    float s = 0.f;
#pragma unroll
    for (int j = 0; j < 12; ++j) s = fmaf(fdr[j], Vb[j * 64], s);
    out[(size_t)img * 4096 + (p0 + pr) * 64 + q] = s;
  }
}

extern "C" void kernel_launch(void* const* d_in, const int* in_sizes, int n_in,
                              void* d_out, int out_size, void* d_ws, size_t ws_size,
                              hipStream_t stream) {
  const float* x   = (const float*)d_in[0];
  const float* w   = (const float*)d_in[1];
  const float* aw  = (const float*)d_in[2];
  const float* ab  = (const float*)d_in[3];
  const float* cw  = (const float*)d_in[4];
  const float* cb  = (const float*)d_in[5];
  const float* fu  = (const float*)d_in[6];
  const float* fd  = (const float*)d_in[7];
  const float* ema = (const float*)d_in[8];
  float* out = (float*)d_out;

  float* ws      = (float*)d_ws;
  float* convout = ws;                          // 17,842,176 f32
  float* styles  = convout + 17842176;          // 4096
  float* wsq     = styles + 4096;               // 262,144
  float* wscale  = wsq + 262144;                // 512
  float* coef    = wscale + 512;                // 4096
  float* sg      = coef + 4096;                 // 8 (pad)
  _Float16* xT   = (_Float16*)(sg + 8);         // 16,777,216 halfs
  _Float16* w2   = (_Float16*)((float*)(sg + 8) + 8388608); // 2,359,296 halfs

  k_styles<<<16, 256, 0, stream>>>(w, aw, ab, styles);
  k_sg<<<1, 256, 0, stream>>>(styles, sg);
  k_wstats<<<512, 256, 0, stream>>>(cw, wsq, wscale);
  k_coef<<<16, 256, 0, stream>>>(styles, wsq, wscale, sg, ema, coef);
  k_xprep<<<8192, 256, 0, stream>>>(x, styles, sg, xT);
  k_wprep<<<1152, 256, 0, stream>>>(cw, wscale, w2);
  k_conv<<<704, 256, 0, stream>>>(xT, w2, coef, convout);
  k_flrelu<<<16384, 256, 0, stream>>>(convout, cb, fu, fd, out);
}

// Round 6
// 647.513 us; speedup vs baseline: 1.1725x; 1.1725x over previous
//
#include <hip/hip_runtime.h>
#include <cstdint>

#define DEV __device__ __forceinline__

static constexpr float INV_SQRT_W = 0.04419417382415922f; // 1/sqrt(512)

typedef _Float16 half8 __attribute__((ext_vector_type(8)));
typedef float    f32x4 __attribute__((ext_vector_type(4)));

DEV int imax(int a, int b) { return a > b ? a : b; }
DEV int imin(int a, int b) { return a < b ? a : b; }

// styles[n][c] = w[n]·aw[c] / sqrt(512) + ab[c]
__global__ __launch_bounds__(256) void k_styles(const float* __restrict__ w,
    const float* __restrict__ aw, const float* __restrict__ ab,
    float* __restrict__ styles) {
  int t = blockIdx.x * 256 + threadIdx.x;        // 4096
  int n = t >> 9, c = t & 511;
  const float* wr = w + n * 512;
  const float* ar = aw + c * 512;
  float s = 0.f;
  for (int k = 0; k < 512; ++k) s = fmaf(wr[k], ar[k], s);
  styles[t] = s * INV_SQRT_W + ab[c];
}

// wsq[o][i] = sum_k w[o,i,k]^2 ; wscale[o] = rsqrt(mean over 4608)
__global__ __launch_bounds__(256) void k_wstats(const float* __restrict__ cw,
    float* __restrict__ wsq, float* __restrict__ wscale) {
  int o = blockIdx.x;
  __shared__ float red[256];
  float tot = 0.f;
  for (int i = threadIdx.x; i < 512; i += 256) {
    const float* p = cw + (o * 512 + i) * 9;
    float s = 0.f;
#pragma unroll
    for (int k = 0; k < 9; ++k) s = fmaf(p[k], p[k], s);
    wsq[o * 512 + i] = s;
    tot += s;
  }
  red[threadIdx.x] = tot;
  __syncthreads();
  for (int st = 128; st > 0; st >>= 1) {
    if (threadIdx.x < st) red[threadIdx.x] += red[threadIdx.x + st];
    __syncthreads();
  }
  if (threadIdx.x == 0) wscale[o] = rsqrtf(red[0] / 4608.f);
}

// sg = rsqrt(mean(styles^2)) over all 4096
__global__ __launch_bounds__(256) void k_sg(const float* __restrict__ styles,
                                            float* __restrict__ sg) {
  __shared__ float red[256];
  float s = 0.f;
  for (int t = threadIdx.x; t < 4096; t += 256) { float v = styles[t]; s = fmaf(v, v, s); }
  red[threadIdx.x] = s;
  __syncthreads();
  for (int st = 128; st > 0; st >>= 1) {
    if (threadIdx.x < st) red[threadIdx.x] += red[threadIdx.x + st];
    __syncthreads();
  }
  if (threadIdx.x == 0) sg[0] = rsqrtf(red[0] / 4096.f);
}

// coef[n][o] = ig * rsqrt(a^2*Q + 1e-8), a = wscale[o]*sg
__global__ __launch_bounds__(256) void k_coef(const float* __restrict__ styles,
    const float* __restrict__ wsq, const float* __restrict__ wscale,
    const float* __restrict__ sg, const float* __restrict__ ema,
    float* __restrict__ coef) {
  int n = blockIdx.x >> 1;
  int o = ((blockIdx.x & 1) << 8) + threadIdx.x;
  __shared__ float s2[512];
  for (int i = threadIdx.x; i < 512; i += 256) { float v = styles[n * 512 + i]; s2[i] = v * v; }
  __syncthreads();
  const float* wq = wsq + o * 512;
  float Q = 0.f;
  for (int i = 0; i < 512; ++i) Q = fmaf(s2[i], wq[i], Q);
  float a = wscale[o] * sg[0];
  float ig = rsqrtf(ema[0]);
  coef[n * 512 + o] = ig * rsqrtf(a * a * Q + 1e-8f);
}

// Padded xT[n][ic][rp 0..67][cp 0..67][i32]: rp=r+2, cp=c+2, zero halo of 2.
// xT[...] = f16( x[n, ic*32+s*8+j, r, c] * styles * sg ), slot s at cp*32+s*8.
__global__ __launch_bounds__(256) void k_xprep(const float* __restrict__ x,
    const float* __restrict__ styles, const float* __restrict__ sg,
    _Float16* __restrict__ xT) {
  const int b = blockIdx.x;                 // 8*16*68 = 8704
  const int rp = b % 68;
  const int ic = (b / 68) % 16;
  const int n = b / (68 * 16);
  const int tid = threadIdx.x;
  const float sgv = sg[0];
  _Float16* base = xT + ((size_t)((n * 16 + ic) * 68 + rp)) * 68 * 32;
  const bool rowpad = (rp < 2) | (rp >= 66);
  for (int t = tid; t < 272; t += 256) {    // 68 px * 4 slots, unit = 8 halfs at t*8
    int cp = t >> 2, s = t & 3;
    half8 v = {};
    if (!rowpad && cp >= 2 && cp < 66) {
      int r = rp - 2, c = cp - 2;
      int i0 = ic * 32 + s * 8;
#pragma unroll
      for (int j = 0; j < 8; ++j) {
        int i = i0 + j;
        float xv = x[(((size_t)n * 512 + i) * 64 + r) * 64 + c];
        v[j] = (_Float16)(xv * styles[n * 512 + i] * sgv);
      }
    }
    *(half8*)(base + t * 8) = v;
  }
}

// w2[k9][ic][o][i32] = f16( cw[o, ic*32+i, k9] * wscale[o] )
__global__ __launch_bounds__(256) void k_wprep(const float* __restrict__ cw,
    const float* __restrict__ wscale, _Float16* __restrict__ w2) {
  int t = blockIdx.x * 256 + threadIdx.x;    // 294912 slots of 8 halfs
  int s = t & 3;
  int o = (t >> 2) & 511;
  int ic = (t >> 11) & 15;
  int k9 = t >> 15;                          // 0..8
  float wsc = wscale[o];
  half8 v;
#pragma unroll
  for (int j = 0; j < 8; ++j) {
    int i = ic * 32 + s * 8 + j;
    v[j] = (_Float16)(cw[((size_t)o * 512 + i) * 9 + k9] * wsc);
  }
  *(half8*)(w2 + (size_t)t * 8) = v;
}

// Implicit-GEMM conv via MFMA f16 — LDS-free, barrier-free.
// Block: 128 o x 128 p, 4 waves (2 o x 2 p), wave = 64 o x 64 p, acc[4][4] (64 regs).
// A (weights) and B (padded-xT patch) both streamed from global; each wave
// fragment load = 16 full 64B lines (fully coalesced). XCD swizzle: 1120 = 8*140,
// each XCD owns one image n.
__global__ __launch_bounds__(256, 3) void k_conv(
    const _Float16* __restrict__ xT, const _Float16* __restrict__ w2,
    const float* __restrict__ coef, _Float16* __restrict__ convout) {
  const int b = blockIdx.x;
  const int lin = (b & 7) * 140 + (b >> 3);
  const int n = lin / 140;
  const int rem = lin - n * 140;
  const int pt = rem >> 2;                 // 0..34
  const int ot = rem & 3;                  // 0..3
  const int p0 = pt * 128;
  const int oBase = ot * 128;

  const int tid = threadIdx.x;
  const int wave = tid >> 6;
  const int lane = tid & 63;
  const int wo = wave >> 1, wp = wave & 1;
  const int isub = lane >> 4;
  const int l15 = lane & 15;

  // per-nt pixel coords; padded layout: tap (dr,dc) -> offset ((r+dr)*68 + c+dc)*32
  int pixb[4]; bool valid[4];
#pragma unroll
  for (int nt = 0; nt < 4; ++nt) {
    int p = p0 + wp * 64 + nt * 16 + l15;
    valid[nt] = (p < 4356);
    if (!valid[nt]) p = 4355;
    int r = p / 66;
    int c = p - r * 66;
    pixb[nt] = (r * 68 + c) * 32 + isub * 8;
  }

  f32x4 acc[4][4];
#pragma unroll
  for (int mt = 0; mt < 4; ++mt)
#pragma unroll
    for (int nt = 0; nt < 4; ++nt) acc[mt][nt] = (f32x4){0.f, 0.f, 0.f, 0.f};

  const _Float16* xb = xT + (size_t)n * 2367488;   // n*16*68*68*32
  const _Float16* wb = w2 + (size_t)(oBase + wo * 64 + l15) * 32 + isub * 8;

  for (int ic = 0; ic < 16; ++ic) {
    const _Float16* xic = xb + ic * 147968;        // 68*68*32
#pragma unroll
    for (int k9 = 0; k9 < 9; ++k9) {
      const int d = (k9 / 3) * 68 + (k9 % 3);
      half8 aF[4];
#pragma unroll
      for (int mt = 0; mt < 4; ++mt)
        aF[mt] = *(const half8*)(wb + (k9 * 16 + ic) * 16384 + mt * 512);
#pragma unroll
      for (int nt = 0; nt < 4; ++nt) {
        half8 bF = *(const half8*)(xic + pixb[nt] + d * 32);
#pragma unroll
        for (int mt = 0; mt < 4; ++mt)
          acc[mt][nt] = __builtin_amdgcn_mfma_f32_16x16x32_f16(aF[mt], bF, acc[mt][nt], 0, 0, 0);
      }
    }
  }

  // epilogue: C layout col=l15 (p), row=isub*4+j (o); scale by coef; f16 store
#pragma unroll
  for (int mt = 0; mt < 4; ++mt) {
    const int o = oBase + wo * 64 + mt * 16 + isub * 4;
#pragma unroll
    for (int j = 0; j < 4; ++j) {
      const float cf = coef[n * 512 + o + j];
      _Float16* outp = convout + (size_t)(n * 512 + o + j) * 4356;
#pragma unroll
      for (int nt = 0; nt < 4; ++nt) {
        if (valid[nt]) {
          int p = p0 + wp * 64 + nt * 16 + l15;
          outp[p] = (_Float16)(acc[mt][nt][j] * cf);
        }
      }
    }
  }
}

// Fused bias + up-FIR(x2, polyphase) + lrelu + clamp + down-FIR(/2).
// NO cross-lane LDS sharing (R3 lesson). R4-verified formulas, tile 16->32 rows.
// Block = one (n,c) image x 32 output rows; reads f16 convout.
__global__ __launch_bounds__(256) void k_flrelu(const _Float16* __restrict__ convout,
    const float* __restrict__ cbias, const float* __restrict__ fu,
    const float* __restrict__ fd, float* __restrict__ out) {
  const int img = blockIdx.x >> 1;       // n*512+c
  const int tile = blockIdx.x & 1;
  const int P0 = tile * 32;              // output rows [P0, P0+32)
  const int c = img & 511;
  const int tid = threadIdx.x;
  const int wv = tid >> 6, ln = tid & 63;

  __shared__ float As[42 * 68];          // conv rows P0-4 .. P0+37 (+bias), 0 outside
  __shared__ float Bs[74 * 76];          // v-up rows, col offset +4, zero aprons
  __shared__ float Vs[74 * 64];          // after horizontal up+lrelu+down

  float fupr[12], fdr[12];
#pragma unroll
  for (int j = 0; j < 12; ++j) { fupr[j] = fu[j]; fdr[j] = fd[11 - j]; }

  // stage 1: A rows [P0-4, P0+37] + bias; zero outside image
  {
    const _Float16* src = convout + (size_t)img * 4356;
    const float bias = cbias[c];
    for (int t = tid; t < 42 * 68; t += 256) {
      int r = t / 68, cc2 = t - r * 68;
      int gr = P0 - 4 + r;
      float v = 0.f;
      if (cc2 < 66 && gr >= 0 && gr < 66) v = (float)src[gr * 66 + cc2] + bias;
      As[t] = v;
    }
  }
  __syncthreads();

  // stage 2: vertical up-FIR, polyphase 6 taps. B[k][m], k in [0,74), m in [0,66).
  // r = 2P0+k, e = k&1, kk = (k-e)/2; A row idx = kk+5-j, tap fup[e+2j].
  for (int t = tid; t < 74 * 33; t += 256) {
    int k = t / 33, m2 = t - k * 33;
    int e = k & 1, kk = (k - e) >> 1;
    const float* Ab = &As[kk * 68 + 2 * m2];
    float sx = 0.f, sy = 0.f;
#pragma unroll
    for (int j = 0; j < 6; ++j) {
      float2 a = *(const float2*)(Ab + (5 - j) * 68);
      float f = e ? fupr[2 * j + 1] : fupr[2 * j];
      sx = fmaf(f, a.x, sx);
      sy = fmaf(f, a.y, sy);
    }
    float2 s2v = make_float2(sx, sy);
    *(float2*)&Bs[k * 76 + 4 + 2 * m2] = s2v;
  }
  for (int t = tid; t < 74 * 10; t += 256) {
    int k = t / 10, ci = t - k * 10;
    int col = (ci < 4) ? ci : (66 + ci);
    Bs[k * 76 + col] = 0.f;
  }
  __syncthreads();

  // stage 3: per-lane recompute of upsampled row + lrelu + horizontal down
  for (int k = wv; k < 74; k += 4) {
    const float* Br = &Bs[k * 76 + ln];
    float bb2[11];
#pragma unroll
    for (int t = 0; t < 11; ++t) bb2[t] = Br[t];
    float v = 0.f;
#pragma unroll
    for (int d = 0; d < 6; ++d) {
      float ue = 0.f, uo = 0.f;
#pragma unroll
      for (int j = 0; j < 6; ++j) {
        float bb = bb2[d + 5 - j];
        ue = fmaf(fupr[2 * j], bb, ue);
        uo = fmaf(fupr[2 * j + 1], bb, uo);
      }
      ue *= (ue >= 0.f) ? 5.65685424949238f : 1.13137084989848f;
      uo *= (uo >= 0.f) ? 5.65685424949238f : 1.13137084989848f;
      ue = fminf(256.f, fmaxf(-256.f, ue));
      uo = fminf(256.f, fmaxf(-256.f, uo));
      v = fmaf(fdr[2 * d], ue, v);
      v = fmaf(fdr[2 * d + 1], uo, v);
    }
    Vs[k * 64 + ln] = v;
  }
  __syncthreads();

  // stage 4: vertical down-FIR -> out rows [P0, P0+32)
  for (int t = tid; t < 2048; t += 256) {
    int pr = t >> 6, q = t & 63;
    const float* Vb = &Vs[2 * pr * 64 + q];
    float s = 0.f;
#pragma unroll
    for (int j = 0; j < 12; ++j) s = fmaf(fdr[j], Vb[j * 64], s);
    out[(size_t)img * 4096 + (P0 + pr) * 64 + q] = s;
  }
}

extern "C" void kernel_launch(void* const* d_in, const int* in_sizes, int n_in,
                              void* d_out, int out_size, void* d_ws, size_t ws_size,
                              hipStream_t stream) {
  const float* x   = (const float*)d_in[0];
  const float* w   = (const float*)d_in[1];
  const float* aw  = (const float*)d_in[2];
  const float* ab  = (const float*)d_in[3];
  const float* cw  = (const float*)d_in[4];
  const float* cb  = (const float*)d_in[5];
  const float* fu  = (const float*)d_in[6];
  const float* fd  = (const float*)d_in[7];
  const float* ema = (const float*)d_in[8];
  float* out = (float*)d_out;

  float* ws       = (float*)d_ws;
  float* styles   = ws;                         // 4096
  float* wsq      = styles + 4096;              // 262144
  float* wscale   = wsq + 262144;               // 512
  float* coef     = wscale + 512;               // 4096
  float* sg       = coef + 4096;                // 8
  _Float16* convout = (_Float16*)(sg + 8);      // 17,842,176 halfs
  _Float16* xT    = convout + 17842176;         // 18,939,904 halfs (padded 68x68)
  _Float16* w2    = xT + 18939904;              // 2,359,296 halfs

  k_styles<<<16, 256, 0, stream>>>(w, aw, ab, styles);
  k_sg<<<1, 256, 0, stream>>>(styles, sg);
  k_wstats<<<512, 256, 0, stream>>>(cw, wsq, wscale);
  k_coef<<<16, 256, 0, stream>>>(styles, wsq, wscale, sg, ema, coef);
  k_xprep<<<8704, 256, 0, stream>>>(x, styles, sg, xT);
  k_wprep<<<1152, 256, 0, stream>>>(cw, wscale, w2);
  k_conv<<<1120, 256, 0, stream>>>(xT, w2, coef, convout);
  k_flrelu<<<8192, 256, 0, stream>>>(convout, cb, fu, fd, out);
}

// Round 7
// 567.311 us; speedup vs baseline: 1.3382x; 1.1414x over previous
//
#include <hip/hip_runtime.h>
#include <cstdint>

#define DEV __device__ __forceinline__

static constexpr float INV_SQRT_W = 0.04419417382415922f; // 1/sqrt(512)

typedef _Float16 half8 __attribute__((ext_vector_type(8)));
typedef float    f32x4 __attribute__((ext_vector_type(4)));

DEV int imax(int a, int b) { return a > b ? a : b; }
DEV int imin(int a, int b) { return a < b ? a : b; }

// styles[n][c] = w[n]·aw[c] / sqrt(512) + ab[c]
__global__ __launch_bounds__(256) void k_styles(const float* __restrict__ w,
    const float* __restrict__ aw, const float* __restrict__ ab,
    float* __restrict__ styles) {
  int t = blockIdx.x * 256 + threadIdx.x;        // 4096
  int n = t >> 9, c = t & 511;
  const float* wr = w + n * 512;
  const float* ar = aw + c * 512;
  float s = 0.f;
  for (int k = 0; k < 512; ++k) s = fmaf(wr[k], ar[k], s);
  styles[t] = s * INV_SQRT_W + ab[c];
}

// wsq[o][i] = sum_k w[o,i,k]^2 ; wscale[o] = rsqrt(mean over 4608)
__global__ __launch_bounds__(256) void k_wstats(const float* __restrict__ cw,
    float* __restrict__ wsq, float* __restrict__ wscale) {
  int o = blockIdx.x;
  __shared__ float red[256];
  float tot = 0.f;
  for (int i = threadIdx.x; i < 512; i += 256) {
    const float* p = cw + (o * 512 + i) * 9;
    float s = 0.f;
#pragma unroll
    for (int k = 0; k < 9; ++k) s = fmaf(p[k], p[k], s);
    wsq[o * 512 + i] = s;
    tot += s;
  }
  red[threadIdx.x] = tot;
  __syncthreads();
  for (int st = 128; st > 0; st >>= 1) {
    if (threadIdx.x < st) red[threadIdx.x] += red[threadIdx.x + st];
    __syncthreads();
  }
  if (threadIdx.x == 0) wscale[o] = rsqrtf(red[0] / 4608.f);
}

// sg = rsqrt(mean(styles^2)) over all 4096
__global__ __launch_bounds__(256) void k_sg(const float* __restrict__ styles,
                                            float* __restrict__ sg) {
  __shared__ float red[256];
  float s = 0.f;
  for (int t = threadIdx.x; t < 4096; t += 256) { float v = styles[t]; s = fmaf(v, v, s); }
  red[threadIdx.x] = s;
  __syncthreads();
  for (int st = 128; st > 0; st >>= 1) {
    if (threadIdx.x < st) red[threadIdx.x] += red[threadIdx.x + st];
    __syncthreads();
  }
  if (threadIdx.x == 0) sg[0] = rsqrtf(red[0] / 4096.f);
}

// coef[n][o] = ig * rsqrt(a^2*Q + 1e-8), a = wscale[o]*sg
__global__ __launch_bounds__(256) void k_coef(const float* __restrict__ styles,
    const float* __restrict__ wsq, const float* __restrict__ wscale,
    const float* __restrict__ sg, const float* __restrict__ ema,
    float* __restrict__ coef) {
  int n = blockIdx.x >> 1;
  int o = ((blockIdx.x & 1) << 8) + threadIdx.x;
  __shared__ float s2[512];
  for (int i = threadIdx.x; i < 512; i += 256) { float v = styles[n * 512 + i]; s2[i] = v * v; }
  __syncthreads();
  const float* wq = wsq + o * 512;
  float Q = 0.f;
  for (int i = 0; i < 512; ++i) Q = fmaf(s2[i], wq[i], Q);
  float a = wscale[o] * sg[0];
  float ig = rsqrtf(ema[0]);
  coef[n * 512 + o] = ig * rsqrtf(a * a * Q + 1e-8f);
}

// Padded xT[n][ic][rp 0..67][cp 0..67][i32]: rp=r+2, cp=c+2, zero halo of 2.
__global__ __launch_bounds__(256) void k_xprep(const float* __restrict__ x,
    const float* __restrict__ styles, const float* __restrict__ sg,
    _Float16* __restrict__ xT) {
  const int b = blockIdx.x;                 // 8*16*68 = 8704
  const int rp = b % 68;
  const int ic = (b / 68) % 16;
  const int n = b / (68 * 16);
  const int tid = threadIdx.x;
  const float sgv = sg[0];
  _Float16* base = xT + ((size_t)((n * 16 + ic) * 68 + rp)) * 68 * 32;
  const bool rowpad = (rp < 2) | (rp >= 66);
  for (int t = tid; t < 272; t += 256) {    // 68 px * 4 slots, unit = 8 halfs at t*8
    int cp = t >> 2, s = t & 3;
    half8 v = {};
    if (!rowpad && cp >= 2 && cp < 66) {
      int r = rp - 2, c = cp - 2;
      int i0 = ic * 32 + s * 8;
#pragma unroll
      for (int j = 0; j < 8; ++j) {
        int i = i0 + j;
        float xv = x[(((size_t)n * 512 + i) * 64 + r) * 64 + c];
        v[j] = (_Float16)(xv * styles[n * 512 + i] * sgv);
      }
    }
    *(half8*)(base + t * 8) = v;
  }
}

// w2[k9][ic][o][i32] = f16( cw[o, ic*32+i, k9] * wscale[o] )
__global__ __launch_bounds__(256) void k_wprep(const float* __restrict__ cw,
    const float* __restrict__ wscale, _Float16* __restrict__ w2) {
  int t = blockIdx.x * 256 + threadIdx.x;    // 294912 slots of 8 halfs
  int s = t & 3;
  int o = (t >> 2) & 511;
  int ic = (t >> 11) & 15;
  int k9 = t >> 15;                          // 0..8
  float wsc = wscale[o];
  half8 v;
#pragma unroll
  for (int j = 0; j < 8; ++j) {
    int i = ic * 32 + s * 8 + j;
    v[j] = (_Float16)(cw[((size_t)o * 512 + i) * 9 + k9] * wsc);
  }
  *(half8*)(w2 + (size_t)t * 8) = v;
}

// Implicit-GEMM conv via MFMA f16 — LDS-free, barrier-free, 1-deep SW pipeline.
// Block: 128 o x 128 p, 4 waves (2 o x 2 p), wave = 64 o x 64 p, acc[4][4].
// Flattened 144-stage (ic,k9) loop; named double buffers (a0,b0)/(a1,b1).
__global__ __launch_bounds__(256, 3) void k_conv(
    const _Float16* __restrict__ xT, const _Float16* __restrict__ w2,
    const float* __restrict__ coef, _Float16* __restrict__ convout) {
  const int b = blockIdx.x;
  const int lin = (b & 7) * 140 + (b >> 3);
  const int n = lin / 140;
  const int rem = lin - n * 140;
  const int pt = rem >> 2;                 // 0..34
  const int ot = rem & 3;                  // 0..3
  const int p0 = pt * 128;
  const int oBase = ot * 128;

  const int tid = threadIdx.x;
  const int wave = tid >> 6;
  const int lane = tid & 63;
  const int wo = wave >> 1, wp = wave & 1;
  const int isub = lane >> 4;
  const int l15 = lane & 15;

  int pixb[4]; bool valid[4];
#pragma unroll
  for (int nt = 0; nt < 4; ++nt) {
    int p = p0 + wp * 64 + nt * 16 + l15;
    valid[nt] = (p < 4356);
    if (!valid[nt]) p = 4355;
    int r = p / 66;
    int c = p - r * 66;
    pixb[nt] = (r * 68 + c) * 32 + isub * 8;
  }

  f32x4 acc[4][4];
#pragma unroll
  for (int mt = 0; mt < 4; ++mt)
#pragma unroll
    for (int nt = 0; nt < 4; ++nt) acc[mt][nt] = (f32x4){0.f, 0.f, 0.f, 0.f};

  const _Float16* xb = xT + (size_t)n * 2367488;   // n*16*68*68*32
  const _Float16* wb = w2 + (size_t)(oBase + wo * 64 + l15) * 32 + isub * 8;

  int k9L = 0, icL = 0;   // wave-uniform load stage counters
  auto LOADF = [&](half8 (&a)[4], half8 (&b8)[4]) {
    const int dr3 = k9L / 3;
    const int d = dr3 * 68 + (k9L - dr3 * 3);
    const _Float16* wrow = wb + (size_t)(k9L * 16 + icL) * 16384;
    const _Float16* xic = xb + icL * 147968 + d * 32;
#pragma unroll
    for (int mt = 0; mt < 4; ++mt) a[mt] = *(const half8*)(wrow + mt * 512);
#pragma unroll
    for (int nt = 0; nt < 4; ++nt) b8[nt] = *(const half8*)(xic + pixb[nt]);
    ++k9L; if (k9L == 9) { k9L = 0; ++icL; }
  };
  auto MFMA4 = [&](half8 (&a)[4], half8 (&b8)[4]) {
#pragma unroll
    for (int nt = 0; nt < 4; ++nt)
#pragma unroll
      for (int mt = 0; mt < 4; ++mt)
        acc[mt][nt] = __builtin_amdgcn_mfma_f32_16x16x32_f16(a[mt], b8[nt], acc[mt][nt], 0, 0, 0);
  };

  half8 a0[4], b0[4], a1[4], b1[4];
  LOADF(a0, b0);
  for (int it = 0; it < 144; it += 2) {
    LOADF(a1, b1);                    // stage it+1 (always exists: it <= 142)
    MFMA4(a0, b0);                    // compute stage it
    if (it + 2 < 144) LOADF(a0, b0);  // stage it+2
    MFMA4(a1, b1);                    // compute stage it+1
  }

  // epilogue: C layout col=l15 (p), row=isub*4+j (o); scale by coef; f16 store
#pragma unroll
  for (int mt = 0; mt < 4; ++mt) {
    const int o = oBase + wo * 64 + mt * 16 + isub * 4;
#pragma unroll
    for (int j = 0; j < 4; ++j) {
      const float cf = coef[n * 512 + o + j];
      _Float16* outp = convout + (size_t)(n * 512 + o + j) * 4356;
#pragma unroll
      for (int nt = 0; nt < 4; ++nt) {
        if (valid[nt]) {
          int p = p0 + wp * 64 + nt * 16 + l15;
          outp[p] = (_Float16)(acc[mt][nt][j] * cf);
        }
      }
    }
  }
}

// Fused bias + up-FIR(x2, polyphase) + lrelu + clamp + down-FIR(/2).
// NO cross-lane LDS sharing (R3 lesson). Verified formulas, 32-row tile.
__global__ __launch_bounds__(256) void k_flrelu(const _Float16* __restrict__ convout,
    const float* __restrict__ cbias, const float* __restrict__ fu,
    const float* __restrict__ fd, float* __restrict__ out) {
  const int img = blockIdx.x >> 1;       // n*512+c
  const int tile = blockIdx.x & 1;
  const int P0 = tile * 32;              // output rows [P0, P0+32)
  const int c = img & 511;
  const int tid = threadIdx.x;
  const int wv = tid >> 6, ln = tid & 63;

  __shared__ float As[42 * 68];          // conv rows P0-4 .. P0+37 (+bias), 0 outside
  __shared__ float Bs[74 * 76];          // v-up rows, col offset +4, zero aprons
  __shared__ float Vs[74 * 64];          // after horizontal up+lrelu+down

  float fupr[12], fdr[12];
#pragma unroll
  for (int j = 0; j < 12; ++j) { fupr[j] = fu[j]; fdr[j] = fd[11 - j]; }

  // stage 1: A rows [P0-4, P0+37] + bias; zero outside image
  {
    const _Float16* src = convout + (size_t)img * 4356;
    const float bias = cbias[c];
    for (int t = tid; t < 42 * 68; t += 256) {
      int r = t / 68, cc2 = t - r * 68;
      int gr = P0 - 4 + r;
      float v = 0.f;
      if (cc2 < 66 && gr >= 0 && gr < 66) v = (float)src[gr * 66 + cc2] + bias;
      As[t] = v;
    }
  }
  __syncthreads();

  // stage 2: vertical up-FIR, polyphase 6 taps
  for (int t = tid; t < 74 * 33; t += 256) {
    int k = t / 33, m2 = t - k * 33;
    int e = k & 1, kk = (k - e) >> 1;
    const float* Ab = &As[kk * 68 + 2 * m2];
    float sx = 0.f, sy = 0.f;
#pragma unroll
    for (int j = 0; j < 6; ++j) {
      float2 a = *(const float2*)(Ab + (5 - j) * 68);
      float f = e ? fupr[2 * j + 1] : fupr[2 * j];
      sx = fmaf(f, a.x, sx);
      sy = fmaf(f, a.y, sy);
    }
    float2 s2v = make_float2(sx, sy);
    *(float2*)&Bs[k * 76 + 4 + 2 * m2] = s2v;
  }
  for (int t = tid; t < 74 * 10; t += 256) {
    int k = t / 10, ci = t - k * 10;
    int col = (ci < 4) ? ci : (66 + ci);
    Bs[k * 76 + col] = 0.f;
  }
  __syncthreads();

  // stage 3: per-lane recompute of upsampled row + lrelu + horizontal down
  for (int k = wv; k < 74; k += 4) {
    const float* Br = &Bs[k * 76 + ln];
    float bb2[11];
#pragma unroll
    for (int t = 0; t < 11; ++t) bb2[t] = Br[t];
    float v = 0.f;
#pragma unroll
    for (int d = 0; d < 6; ++d) {
      float ue = 0.f, uo = 0.f;
#pragma unroll
      for (int j = 0; j < 6; ++j) {
        float bb = bb2[d + 5 - j];
        ue = fmaf(fupr[2 * j], bb, ue);
        uo = fmaf(fupr[2 * j + 1], bb, uo);
      }
      ue *= (ue >= 0.f) ? 5.65685424949238f : 1.13137084989848f;
      uo *= (uo >= 0.f) ? 5.65685424949238f : 1.13137084989848f;
      ue = fminf(256.f, fmaxf(-256.f, ue));
      uo = fminf(256.f, fmaxf(-256.f, uo));
      v = fmaf(fdr[2 * d], ue, v);
      v = fmaf(fdr[2 * d + 1], uo, v);
    }
    Vs[k * 64 + ln] = v;
  }
  __syncthreads();

  // stage 4: vertical down-FIR -> out rows [P0, P0+32)
  for (int t = tid; t < 2048; t += 256) {
    int pr = t >> 6, q = t & 63;
    const float* Vb = &Vs[2 * pr * 64 + q];
    float s = 0.f;
#pragma unroll
    for (int j = 0; j < 12; ++j) s = fmaf(fdr[j], Vb[j * 64], s);
    out[(size_t)img * 4096 + (P0 + pr) * 64 + q] = s;
  }
}

extern "C" void kernel_launch(void* const* d_in, const int* in_sizes, int n_in,
                              void* d_out, int out_size, void* d_ws, size_t ws_size,
                              hipStream_t stream) {
  const float* x   = (const float*)d_in[0];
  const float* w   = (const float*)d_in[1];
  const float* aw  = (const float*)d_in[2];
  const float* ab  = (const float*)d_in[3];
  const float* cw  = (const float*)d_in[4];
  const float* cb  = (const float*)d_in[5];
  const float* fu  = (const float*)d_in[6];
  const float* fd  = (const float*)d_in[7];
  const float* ema = (const float*)d_in[8];
  float* out = (float*)d_out;

  float* ws       = (float*)d_ws;
  float* styles   = ws;                         // 4096
  float* wsq      = styles + 4096;              // 262144
  float* wscale   = wsq + 262144;               // 512
  float* coef     = wscale + 512;               // 4096
  float* sg       = coef + 4096;                // 8
  _Float16* convout = (_Float16*)(sg + 8);      // 17,842,176 halfs
  _Float16* xT    = convout + 17842176;         // 18,939,904 halfs (padded 68x68)
  _Float16* w2    = xT + 18939904;              // 2,359,296 halfs

  k_styles<<<16, 256, 0, stream>>>(w, aw, ab, styles);
  k_sg<<<1, 256, 0, stream>>>(styles, sg);
  k_wstats<<<512, 256, 0, stream>>>(cw, wsq, wscale);
  k_coef<<<16, 256, 0, stream>>>(styles, wsq, wscale, sg, ema, coef);
  k_xprep<<<8704, 256, 0, stream>>>(x, styles, sg, xT);
  k_wprep<<<1152, 256, 0, stream>>>(cw, wscale, w2);
  k_conv<<<1120, 256, 0, stream>>>(xT, w2, coef, convout);
  k_flrelu<<<8192, 256, 0, stream>>>(convout, cb, fu, fd, out);
}